// Round 16
// baseline (2236.572 us; speedup 1.0000x reference)
//
#include <hip/hip_runtime.h>
#include <cstdint>

#define F0 100
#define FH 128
#define FO 64
#define PD 4
#define SB 128
#define BN_EPS 1e-5f

typedef unsigned short ushort_t;
typedef unsigned int uint_t;
typedef __attribute__((ext_vector_type(8))) __bf16 bf16x8;
typedef __attribute__((ext_vector_type(4))) float f32x4;

static inline int ceil_div(long long a, long long b) { return (int)((a + b - 1) / b); }

__device__ __forceinline__ float bf_lo(uint_t w) { return __uint_as_float(w << 16); }
__device__ __forceinline__ float bf_hi(uint_t w) { return __uint_as_float(w & 0xffff0000u); }
__device__ __forceinline__ uint_t f2bf(float f) {  // RNE
  uint_t u = __float_as_uint(f);
  return (u + 0x7fffu + ((u >> 16) & 1u)) >> 16;
}
__device__ __forceinline__ uint_t pack2(float a, float b) {
  return f2bf(a) | (f2bf(b) << 16);
}

// ---- epoch grid barrier (all blocks co-resident by construction) ----
__device__ __forceinline__ void grid_barrier(int* bar, int epoch) {
  __syncthreads();
  __threadfence_system();  // release: write back all dirty lines
  if (threadIdx.x == 0) {
    atomicAdd(bar, 1);
    while (atomicAdd(bar, 0) < (int)gridDim.x * epoch) __builtin_amdgcn_s_sleep(8);
  }
  __syncthreads();
  __threadfence_system();  // acquire: invalidate stale lines
}

struct MegaParams {
  const float* x; const int* row; const int* col; const float* ew;
  const float* W0; const float* b0; const float* g0; const float* be0;
  const float* W1; const float* b1; const float* g1; const float* be1;
  const float* W2; const float* b2;
  ushort_t* bufA; ushort_t* bufB; int2* ep;
  int* degc_p; int* degr_p;
  float* sum0; float* sumsq0; float* sum1; float* sumsq1;
  int* ctr; int* bar;
  int* startp; int* degc; float* dinv; int* bsums; int* posw;
  float* scale0; float* shift0; float* scale1; float* shift1;
  float* out;
  int n, E, GB, MB, nb;
};

// ---------------- gemm0 tile: t0[64 x 128] bf16 = x[64 x 100] fp32 @ W0 ----------------

__device__ void gemm0_body(unsigned char* smem, int bid, const float* __restrict__ A,
                           const float* __restrict__ W, ushort_t* __restrict__ out, int n) {
  constexpr int K = F0, BK = 16, TM = 8;
  constexpr int NCG = FH / 4, BR = 64, F4 = FH / 4, K4 = K / 4;
  float (*sW)[FH] = (float(*)[FH])smem;
  float (*sA)[BK] = (float(*)[BK])(smem + BK * FH * 4);

  const int tid = threadIdx.x;
  const int cgi = tid % NCG;
  const int rg = tid / NCG;
  const int row0 = bid * BR;

  float4 acc[TM];
#pragma unroll
  for (int t = 0; t < TM; ++t) acc[t] = make_float4(0.f, 0.f, 0.f, 0.f);

  const float4* A4 = (const float4*)A;
  const float4* W4 = (const float4*)W;
  const float4 z4 = make_float4(0.f, 0.f, 0.f, 0.f);

  for (int k0 = 0; k0 < K; k0 += BK) {
    for (int i = tid; i < BK * F4; i += 256) {
      int kk = i / F4, f4 = i % F4;
      int gk = k0 + kk;
      ((float4*)&sW[kk][0])[f4] = (gk < K) ? W4[(size_t)gk * F4 + f4] : z4;
    }
    for (int i = tid; i < BR * (BK / 4); i += 256) {
      int r = i / (BK / 4), k4 = i % (BK / 4);
      int gr = row0 + r;
      int gk = k0 + k4 * 4;
      float4 av = z4;
      if (gr < n && gk + 3 < K) av = A4[(size_t)gr * K4 + (gk >> 2)];
      ((float4*)&sA[r][0])[k4] = av;
    }
    __syncthreads();
#pragma unroll 4
    for (int kk = 0; kk < BK; ++kk) {
      float4 w = ((const float4*)&sW[kk][0])[cgi];
#pragma unroll
      for (int t = 0; t < TM; ++t) {
        float a = sA[rg * TM + t][kk];
        acc[t].x = fmaf(a, w.x, acc[t].x);
        acc[t].y = fmaf(a, w.y, acc[t].y);
        acc[t].z = fmaf(a, w.z, acc[t].z);
        acc[t].w = fmaf(a, w.w, acc[t].w);
      }
    }
    __syncthreads();
  }

#pragma unroll
  for (int t = 0; t < TM; ++t) {
    int gr = row0 + rg * TM + t;
    if (gr < n) {
      float4 v = acc[t];
      ((uint2*)out)[(size_t)gr * F4 + cgi] = make_uint2(pack2(v.x, v.y), pack2(v.z, v.w));
    }
  }
}

// ---------------- MFMA tile: out[64 x FOUT] bf16 = A[64 x 128] bf16 @ W fp32 ----------------

template <int FOUT, bool BN_A>
__device__ void mfma_body(unsigned char* smem, int bid, const ushort_t* __restrict__ A,
                          const float* __restrict__ W, const float* __restrict__ bias,
                          const float* __restrict__ scA, const float* __restrict__ shA,
                          ushort_t* __restrict__ out, int n) {
  constexpr int F4 = FOUT / 4;
  constexpr int NT = FOUT / 16;
  ushort_t* Wt = (ushort_t*)smem;

  __syncthreads();  // protect smem reuse across successive calls
  const int tid = threadIdx.x;
  const float4* W4 = (const float4*)W;
  uint_t* w32 = (uint_t*)Wt;
  for (int idx = tid; idx < 64 * F4; idx += 256) {
    int kp = idx / F4, cq = idx % F4;
    float4 wa = W4[(size_t)(2 * kp) * F4 + cq];
    float4 wb = W4[(size_t)(2 * kp + 1) * F4 + cq];
    int kq = kp >> 2, e2 = kp & 3;
    int base = (kq * FOUT + cq * 4) * 4 + e2;
    w32[base]      = pack2(wa.x, wb.x);
    w32[base + 4]  = pack2(wa.y, wb.y);
    w32[base + 8]  = pack2(wa.z, wb.z);
    w32[base + 12] = pack2(wa.w, wb.w);
  }
  __syncthreads();

  const int l = tid & 63;
  const int wv = tid >> 6;
  const int cc = l & 15;
  const int h = l >> 4;
  const int rowa = bid * 64 + wv * 16 + cc;
  const int ra = (rowa < n) ? rowa : (n - 1);

  f32x4 acc[NT];
#pragma unroll
  for (int t = 0; t < NT; ++t) acc[t] = (f32x4)0.f;

#pragma unroll
  for (int ks = 0; ks < 4; ++ks) {
    const int k0 = 32 * ks;
    uint4 av = *(const uint4*)(A + (size_t)ra * FH + k0 + 8 * h);
    if (BN_A) {
      const float4* sc4 = (const float4*)(scA + k0 + 8 * h);
      const float4* sh4 = (const float4*)(shA + k0 + 8 * h);
      float4 sa = sc4[0], sb = sc4[1], ha = sh4[0], hb = sh4[1];
      av.x = pack2(fmaxf(fmaf(bf_lo(av.x), sa.x, ha.x), 0.f),
                   fmaxf(fmaf(bf_hi(av.x), sa.y, ha.y), 0.f));
      av.y = pack2(fmaxf(fmaf(bf_lo(av.y), sa.z, ha.z), 0.f),
                   fmaxf(fmaf(bf_hi(av.y), sa.w, ha.w), 0.f));
      av.z = pack2(fmaxf(fmaf(bf_lo(av.z), sb.x, hb.x), 0.f),
                   fmaxf(fmaf(bf_hi(av.z), sb.y, hb.y), 0.f));
      av.w = pack2(fmaxf(fmaf(bf_lo(av.w), sb.z, hb.z), 0.f),
                   fmaxf(fmaf(bf_hi(av.w), sb.w, hb.w), 0.f));
    }
    bf16x8 afrag = __builtin_bit_cast(bf16x8, av);
    const int kq = ks * 4 + h;
#pragma unroll
    for (int ct = 0; ct < NT; ++ct) {
      int c = ct * 16 + cc;
      uint4 bv = *(const uint4*)(Wt + ((size_t)kq * FOUT + c) * 8);
      bf16x8 bfrag = __builtin_bit_cast(bf16x8, bv);
      acc[ct] = __builtin_amdgcn_mfma_f32_16x16x32_bf16(afrag, bfrag, acc[ct], 0, 0, 0);
    }
  }

  const int rbase = bid * 64 + wv * 16 + 4 * h;
#pragma unroll
  for (int ct = 0; ct < NT; ++ct) {
    int c = ct * 16 + cc;
    float bvv = bias ? bias[c] : 0.f;
#pragma unroll
    for (int r = 0; r < 4; ++r) {
      int gr = rbase + r;
      if (gr < n) out[(size_t)gr * FOUT + c] = (ushort_t)f2bf(acc[ct][r] + bvv);
    }
  }
}

// ---------------- conv gather (grid-strided), BN from precomputed scale/shift ----------------

template <int F, bool DO_BN, bool OUT_F32>
__device__ void conv_body(int bid, const ushort_t* __restrict__ x,
                          const int* __restrict__ startp, const int* __restrict__ bsums,
                          const int* __restrict__ degc, const int2* __restrict__ ep,
                          const float* __restrict__ bias, const float* __restrict__ scale,
                          const float* __restrict__ shift, void* __restrict__ out, int n) {
  constexpr int G2 = F / 8;
  constexpr int TPD = G2 / 2;
  const uint4* x4 = (const uint4*)x;
  const long long total = (long long)n * TPD;

  for (long long task = (long long)bid * 256 + threadIdx.x; task < total;
       task += (long long)gridDim.x * 256) {
    int dst = (int)(task / TPD);
    int q = (int)(task % TPD);
    int s0 = startp[dst] + bsums[dst >> 8];
    int d = degc[dst];

    float sc[16], sh[16];
    if (DO_BN) {
#pragma unroll
      for (int ch = 0; ch < 2; ++ch) {
        int gg = q + ch * TPD;
#pragma unroll
        for (int j = 0; j < 8; ++j) {
          sc[ch * 8 + j] = scale[gg * 8 + j];
          sh[ch * 8 + j] = shift[gg * 8 + j];
        }
      }
    }

    float acc[16];
#pragma unroll
    for (int j = 0; j < 16; ++j) acc[j] = 0.f;

    for (int k = 0; k < d; ++k) {
      int2 e = ep[s0 + k];
      float c = __int_as_float(e.y);
      const uint4* xp = x4 + (size_t)e.x * G2 + q;
      uint4 v0 = xp[0];
      uint4 v1 = xp[TPD];
      uint_t vv[8] = {v0.x, v0.y, v0.z, v0.w, v1.x, v1.y, v1.z, v1.w};
#pragma unroll
      for (int hh = 0; hh < 8; ++hh) {
        float f0 = bf_lo(vv[hh]);
        float f1 = bf_hi(vv[hh]);
        if (DO_BN) {
          f0 = fmaxf(fmaf(f0, sc[2 * hh], sh[2 * hh]), 0.f);
          f1 = fmaxf(fmaf(f1, sc[2 * hh + 1], sh[2 * hh + 1]), 0.f);
        }
        acc[2 * hh] = fmaf(c, f0, acc[2 * hh]);
        acc[2 * hh + 1] = fmaf(c, f1, acc[2 * hh + 1]);
      }
    }

    if (bias) {
#pragma unroll
      for (int ch = 0; ch < 2; ++ch) {
        int gg = q + ch * TPD;
#pragma unroll
        for (int j = 0; j < 8; ++j) acc[ch * 8 + j] += bias[gg * 8 + j];
      }
    }

    if (OUT_F32) {
      float4* o4 = (float4*)out;
      size_t base = (size_t)dst * (F / 4);
      o4[base + 2 * q] = make_float4(acc[0], acc[1], acc[2], acc[3]);
      o4[base + 2 * q + 1] = make_float4(acc[4], acc[5], acc[6], acc[7]);
      o4[base + 2 * (q + TPD)] = make_float4(acc[8], acc[9], acc[10], acc[11]);
      o4[base + 2 * (q + TPD) + 1] = make_float4(acc[12], acc[13], acc[14], acc[15]);
    } else {
      uint4* o4 = (uint4*)out;
      size_t base = (size_t)dst * G2;
      o4[base + q] = make_uint4(pack2(acc[0], acc[1]), pack2(acc[2], acc[3]),
                                pack2(acc[4], acc[5]), pack2(acc[6], acc[7]));
      o4[base + q + TPD] = make_uint4(pack2(acc[8], acc[9]), pack2(acc[10], acc[11]),
                                      pack2(acc[12], acc[13]), pack2(acc[14], acc[15]));
    }
  }
}

// ---------------- stats + last-block finalize (R12-proven pattern) ----------------

__device__ void stats_fin_body(unsigned char* smem, int bid, const ushort_t* __restrict__ z,
                               float* __restrict__ sum, float* __restrict__ sumsq,
                               const float* __restrict__ g, const float* __restrict__ be,
                               float* __restrict__ scale, float* __restrict__ shift, int n,
                               int* __restrict__ ctr) {
  float (*red)[8] = (float(*)[8])smem;
  const int tid = threadIdx.x;
  const int q = tid & 15;
  const int rg = tid >> 4;
  const uint4* z4 = (const uint4*)z;

  float s[8], s2[8];
#pragma unroll
  for (int j = 0; j < 8; ++j) { s[j] = 0.f; s2[j] = 0.f; }

  for (int r = bid * 16 + rg; r < n; r += SB * 16) {
    uint4 v = z4[(size_t)r * (FH / 8) + q];
    uint_t vv[4] = {v.x, v.y, v.z, v.w};
#pragma unroll
    for (int h = 0; h < 4; ++h) {
      float f0 = bf_lo(vv[h]);
      float f1 = bf_hi(vv[h]);
      s[2 * h] += f0;      s2[2 * h] += f0 * f0;
      s[2 * h + 1] += f1;  s2[2 * h + 1] += f1 * f1;
    }
  }

#pragma unroll
  for (int j = 0; j < 8; ++j) red[tid][j] = s[j];
  __syncthreads();
  for (int off = 128; off >= 16; off >>= 1) {
    if (tid < off) {
#pragma unroll
      for (int j = 0; j < 8; ++j) red[tid][j] += red[tid + off][j];
    }
    __syncthreads();
  }
  if (tid < 16) {
#pragma unroll
    for (int j = 0; j < 8; ++j) unsafeAtomicAdd(&sum[8 * tid + j], red[tid][j]);
  }
  __syncthreads();
#pragma unroll
  for (int j = 0; j < 8; ++j) red[tid][j] = s2[j];
  __syncthreads();
  for (int off = 128; off >= 16; off >>= 1) {
    if (tid < off) {
#pragma unroll
      for (int j = 0; j < 8; ++j) red[tid][j] += red[tid + off][j];
    }
    __syncthreads();
  }
  if (tid < 16) {
#pragma unroll
    for (int j = 0; j < 8; ++j) unsafeAtomicAdd(&sumsq[8 * tid + j], red[tid][j]);
  }
  __threadfence();
  __syncthreads();
  __shared__ int lastFlag;
  if (tid == 0) lastFlag = (atomicAdd(ctr, 1) == SB - 1) ? 1 : 0;
  __syncthreads();
  if (lastFlag && tid < FH) {
    float S = atomicAdd(&sum[tid], 0.0f);    // coherent re-read
    float S2 = atomicAdd(&sumsq[tid], 0.0f);
    float invN = 1.0f / (float)n;
    float mean = S * invN;
    float var = fmaxf(S2 * invN - mean * mean, 0.0f);
    float scv = g[tid] * rsqrtf(var + BN_EPS);
    scale[tid] = scv;
    shift[tid] = be[tid] - mean * scv;
  }
}

// ---------------- scan body (R12-proven, + plain degc copy) ----------------

__device__ void scan_body(unsigned char* smem, int bid, const MegaParams& p) {
  int* s = (int*)smem;
  const int tid = threadIdx.x;
  int i = bid * 256 + tid;
  int dc = 0;
  if (i < p.n) {
    int dr = p.degr_p[(size_t)i * PD];
    dc = p.degc_p[(size_t)i * PD];
    p.dinv[i] = (dr > 0) ? rsqrtf((float)dr) : 0.f;
    p.degc[i] = dc;
  }
  s[tid] = dc;
  __syncthreads();
  for (int off = 1; off < 256; off <<= 1) {
    int t = 0;
    if (tid >= off) t = s[tid - off];
    __syncthreads();
    if (tid >= off) s[tid] += t;
    __syncthreads();
  }
  if (i < p.n) p.startp[i] = s[tid] - dc;
  if (tid == 255) p.bsums[bid] = s[255];
  __threadfence();
  __syncthreads();
  __shared__ int lastFlag;
  if (tid == 0) lastFlag = (atomicAdd(p.ctr, 1) == p.nb - 1) ? 1 : 0;
  __syncthreads();
  if (!lastFlag) return;
  int v = (tid < p.nb) ? atomicAdd(&p.bsums[tid], 0) : 0;  // coherent re-read
  s[tid] = v;
  __syncthreads();
  for (int off = 1; off < 256; off <<= 1) {
    int t = 0;
    if (tid >= off) t = s[tid - off];
    __syncthreads();
    if (tid >= off) s[tid] += t;
    __syncthreads();
  }
  if (tid < p.nb) p.bsums[tid] = s[tid] - v;  // exclusive
}

// ---------------- the mega kernel ----------------

__global__ __launch_bounds__(256, 4) void mega_kernel(MegaParams p) {
  __shared__ __align__(16) unsigned char smem[32768];
  const int bid = blockIdx.x;
  const int NB = (int)gridDim.x;
  const int tid = threadIdx.x;

  // P1: gemm0 (t0 = x@W0 -> bufA, grid-strided tiles) + histogram (+posw)
  for (int b = bid; b < p.GB; b += NB) gemm0_body(smem, b, p.x, p.W0, p.bufA, p.n);
  for (long long e = (long long)bid * 256 + tid; e < p.E; e += (long long)NB * 256) {
    atomicAdd(&p.degr_p[(size_t)p.row[e] * PD], 1);
    p.posw[e] = atomicAdd(&p.degc_p[(size_t)p.col[e] * PD], 1);
  }
  grid_barrier(p.bar, 1);

  // P2: scan (+dinv, degc copy, fused partials)
  if (bid < p.nb) scan_body(smem, bid, p);
  grid_barrier(p.bar, 2);

  // P3: scatter packed (src, coef)
  for (long long e = (long long)bid * 256 + tid; e < p.E; e += (long long)NB * 256) {
    int r = p.row[e], c = p.col[e];
    int pos = p.startp[c] + p.bsums[c >> 8] + p.posw[e];
    float coef = p.dinv[r] * p.ew[e] * p.dinv[c];
    p.ep[pos] = make_int2(r, __float_as_int(coef));
  }
  grid_barrier(p.bar, 3);

  // P4: z0 = conv(t0) + b0 -> bufB
  conv_body<FH, false, false>(bid, p.bufA, p.startp, p.bsums, p.degc, p.ep, p.b0, nullptr,
                              nullptr, p.bufB, p.n);
  grid_barrier(p.bar, 4);

  // P5: stats0 + finalize -> scale0/shift0
  if (bid < SB) stats_fin_body(smem, bid, p.bufB, p.sum0, p.sumsq0, p.g0, p.be0, p.scale0,
                               p.shift0, p.n, p.ctr + 1);
  grid_barrier(p.bar, 5);

  // P6: conv(relu(bn0(z0))) -> bufA
  conv_body<FH, true, false>(bid, p.bufB, p.startp, p.bsums, p.degc, p.ep, nullptr, p.scale0,
                             p.shift0, p.bufA, p.n);
  grid_barrier(p.bar, 6);

  // P7: z1 = bufA @ W1 + b1 -> bufB (MFMA, grid-strided tiles)
  for (int b = bid; b < p.MB; b += NB)
    mfma_body<FH, false>(smem, b, p.bufA, p.W1, p.b1, nullptr, nullptr, p.bufB, p.n);
  grid_barrier(p.bar, 7);

  // P8: stats1 + finalize -> scale1/shift1
  if (bid < SB) stats_fin_body(smem, bid, p.bufB, p.sum1, p.sumsq1, p.g1, p.be1, p.scale1,
                               p.shift1, p.n, p.ctr + 2);
  grid_barrier(p.bar, 8);

  // P9: t2 = relu(bn1(z1)) @ W2 -> bufA (MFMA, BN on A-loads)
  for (int b = bid; b < p.MB; b += NB)
    mfma_body<FO, true>(smem, b, p.bufB, p.W2, nullptr, p.scale1, p.shift1, p.bufA, p.n);
  grid_barrier(p.bar, 9);

  // P10: out = conv(t2) + b2 -> d_out (fp32)
  conv_body<FO, false, true>(bid, p.bufA, p.startp, p.bsums, p.degc, p.ep, p.b2, nullptr,
                             nullptr, p.out, p.n);
}

// ---------------- launch ----------------

extern "C" void kernel_launch(void* const* d_in, const int* in_sizes, int n_in,
                              void* d_out, int out_size, void* d_ws, size_t ws_size,
                              hipStream_t stream) {
  const int n = in_sizes[0] / F0;
  const int E = in_sizes[2];
  const int* ei = (const int*)d_in[1];

  // workspace layout
  ushort_t* bufA  = (ushort_t*)d_ws;                    // n*FH bf16
  ushort_t* bufB  = bufA + (size_t)n * FH;              // n*FH bf16
  int2*   ep      = (int2*)(bufB + (size_t)n * FH);     // E int2
  // contiguous zero region: [degc_p | degr_p | sums(4*FH) | ctr(3) | bar(1)]
  int*    degc_p  = (int*)(ep + E);
  int*    degr_p  = degc_p + (size_t)n * PD;
  float*  sum0    = (float*)(degr_p + (size_t)n * PD);
  float*  sumsq0  = sum0 + FH;
  float*  sum1    = sumsq0 + FH;
  float*  sumsq1  = sum1 + FH;
  int*    ctr     = (int*)(sumsq1 + FH);                // 3
  int*    bar     = ctr + 3;                            // 1
  const size_t zero_bytes = (2 * (size_t)n * PD + 4 * FH + 4) * 4;
  int*    startp  = bar + 1;                            // n
  int*    degc    = startp + n;                         // n
  float*  dinv    = (float*)(degc + n);                 // n
  int*    bsums   = (int*)(dinv + n);                   // 256
  float*  scale0  = (float*)(bsums + 256);              // 4*FH
  float*  shift0  = scale0 + FH;
  float*  scale1  = shift0 + FH;
  float*  shift1  = scale1 + FH;
  int*    posw    = (int*)bufB;                         // transient alias

  MegaParams p;
  p.x = (const float*)d_in[0];
  p.row = ei; p.col = ei + E;
  p.ew = (const float*)d_in[2];
  p.W0 = (const float*)d_in[3];  p.b0 = (const float*)d_in[4];
  p.g0 = (const float*)d_in[5];  p.be0 = (const float*)d_in[6];
  p.W1 = (const float*)d_in[7];  p.b1 = (const float*)d_in[8];
  p.g1 = (const float*)d_in[9];  p.be1 = (const float*)d_in[10];
  p.W2 = (const float*)d_in[11]; p.b2 = (const float*)d_in[12];
  p.bufA = bufA; p.bufB = bufB; p.ep = ep;
  p.degc_p = degc_p; p.degr_p = degr_p;
  p.sum0 = sum0; p.sumsq0 = sumsq0; p.sum1 = sum1; p.sumsq1 = sumsq1;
  p.ctr = ctr; p.bar = bar;
  p.startp = startp; p.degc = degc; p.dinv = dinv; p.bsums = bsums; p.posw = posw;
  p.scale0 = scale0; p.shift0 = shift0; p.scale1 = scale1; p.shift1 = shift1;
  p.out = (float*)d_out;
  p.n = n; p.E = E;
  p.GB = ceil_div(n, 64);
  p.MB = ceil_div(n, 64);
  p.nb = ceil_div(n, 256);

  int numCU = 0;
  int dev = 0;
  (void)hipGetDevice(&dev);
  (void)hipDeviceGetAttribute(&numCU, hipDeviceAttributeMultiprocessorCount, dev);
  if (numCU <= 0) numCU = 256;
  int NB = numCU * 4;  // guaranteed co-resident via __launch_bounds__(256,4), LDS 32KB
  if (NB < 256) NB = 256;

  (void)hipMemsetAsync(degc_p, 0, zero_bytes, stream);
  mega_kernel<<<NB, 256, 0, stream>>>(p);
}

// Round 17
// 363.622 us; speedup vs baseline: 6.1508x; 6.1508x over previous
//
#include <hip/hip_runtime.h>
#include <cstdint>

#define F0 100
#define FH 128
#define FO 64
#define PD 4  // counter padding (ints)
#define BN_EPS 1e-5f

typedef unsigned short ushort_t;
typedef unsigned int uint_t;
typedef __attribute__((ext_vector_type(8))) __bf16 bf16x8;
typedef __attribute__((ext_vector_type(4))) float f32x4;

static inline int ceil_div(long long a, long long b) { return (int)((a + b - 1) / b); }

// ---- bf16 helpers (fp32 math everywhere; bf16 is storage only) ----
__device__ __forceinline__ float bf_lo(uint_t w) { return __uint_as_float(w << 16); }
__device__ __forceinline__ float bf_hi(uint_t w) { return __uint_as_float(w & 0xffff0000u); }
__device__ __forceinline__ uint_t f2bf(float f) {  // RNE
  uint_t u = __float_as_uint(f);
  return (u + 0x7fffu + ((u >> 16) & 1u)) >> 16;
}
__device__ __forceinline__ uint_t pack2(float a, float b) {
  return f2bf(a) | (f2bf(b) << 16);
}

// ---------------- GEMM body (vector fp32; used for gemm0 inside hist) ----------------

template <int K, int F, int TM, int BK, bool A_BF16, bool OUT_BF16>
__device__ __forceinline__ void gemm2_body(int bid, const void* __restrict__ A_,
                                           const float* __restrict__ W,
                                           const float* __restrict__ bias,
                                           void* __restrict__ out_, int n) {
  constexpr int NCG = F / 4;
  constexpr int NRG = 256 / NCG;
  constexpr int BR = NRG * TM;
  constexpr int F4 = F / 4;

  __shared__ float sW[BK][F];
  __shared__ float sA[BR][BK];

  const int tid = threadIdx.x;
  const int cg = tid % NCG;
  const int rg = tid / NCG;
  const int row0 = bid * BR;

  float4 acc[TM];
#pragma unroll
  for (int t = 0; t < TM; ++t) acc[t] = make_float4(0.f, 0.f, 0.f, 0.f);

  const float4* W4 = (const float4*)W;
  const float4 z4 = make_float4(0.f, 0.f, 0.f, 0.f);

  for (int k0 = 0; k0 < K; k0 += BK) {
    for (int i = tid; i < BK * F4; i += 256) {
      int kk = i / F4, f4 = i % F4;
      int gk = k0 + kk;
      ((float4*)&sW[kk][0])[f4] = (gk < K) ? W4[(size_t)gk * F4 + f4] : z4;
    }
    for (int i = tid; i < BR * (BK / 4); i += 256) {
      int r = i / (BK / 4), k4 = i % (BK / 4);
      int gr = row0 + r;
      int gk = k0 + k4 * 4;
      float4 av = z4;
      if (gr < n && gk + 3 < K) {
        if (A_BF16) {
          uint2 u = ((const uint2*)A_)[(size_t)gr * (K / 4) + (gk >> 2)];
          av.x = bf_lo(u.x); av.y = bf_hi(u.x);
          av.z = bf_lo(u.y); av.w = bf_hi(u.y);
        } else {
          av = ((const float4*)A_)[(size_t)gr * (K / 4) + (gk >> 2)];
        }
      }
      ((float4*)&sA[r][0])[k4] = av;
    }
    __syncthreads();
#pragma unroll 4
    for (int kk = 0; kk < BK; ++kk) {
      float4 w = ((const float4*)&sW[kk][0])[cg];
#pragma unroll
      for (int t = 0; t < TM; ++t) {
        float a = sA[rg * TM + t][kk];
        acc[t].x = fmaf(a, w.x, acc[t].x);
        acc[t].y = fmaf(a, w.y, acc[t].y);
        acc[t].z = fmaf(a, w.z, acc[t].z);
        acc[t].w = fmaf(a, w.w, acc[t].w);
      }
    }
    __syncthreads();
  }

  float4 bb = bias ? ((const float4*)bias)[cg] : z4;
#pragma unroll
  for (int t = 0; t < TM; ++t) {
    int gr = row0 + rg * TM + t;
    if (gr < n) {
      float4 v = acc[t];
      v.x += bb.x; v.y += bb.y; v.z += bb.z; v.w += bb.w;
      if (OUT_BF16) {
        ((uint2*)out_)[(size_t)gr * F4 + cg] = make_uint2(pack2(v.x, v.y), pack2(v.z, v.w));
      } else {
        ((float4*)out_)[(size_t)gr * F4 + cg] = v;
      }
    }
  }
}

// ---------------- MFMA GEMM: out[n x FOUT] bf16 = A[n x 128] bf16 @ W[128 x FOUT] fp32 ----

template <int FOUT, bool BN_A>
__global__ __launch_bounds__(256) void gemm_mfma_kernel(const ushort_t* __restrict__ A,
                                                        const float* __restrict__ W,
                                                        const float* __restrict__ bias,
                                                        const float* __restrict__ scA,
                                                        const float* __restrict__ shA,
                                                        ushort_t* __restrict__ out, int n) {
  constexpr int F4 = FOUT / 4;
  constexpr int NT = FOUT / 16;
  __shared__ ushort_t Wt[16 * FOUT * 8];  // [kq=K/8][c][8 k-elems]

  const int tid = threadIdx.x;
  const float4* W4 = (const float4*)W;
  uint_t* w32 = (uint_t*)Wt;
  for (int idx = tid; idx < 64 * F4; idx += 256) {
    int kp = idx / F4, cq = idx % F4;
    float4 wa = W4[(size_t)(2 * kp) * F4 + cq];
    float4 wb = W4[(size_t)(2 * kp + 1) * F4 + cq];
    int kq = kp >> 2, e2 = kp & 3;
    int base = (kq * FOUT + cq * 4) * 4 + e2;
    w32[base]      = pack2(wa.x, wb.x);
    w32[base + 4]  = pack2(wa.y, wb.y);
    w32[base + 8]  = pack2(wa.z, wb.z);
    w32[base + 12] = pack2(wa.w, wb.w);
  }
  __syncthreads();

  const int l = tid & 63;
  const int wv = tid >> 6;
  const int cc = l & 15;
  const int h = l >> 4;
  const int rowa = blockIdx.x * 64 + wv * 16 + cc;
  const int ra = (rowa < n) ? rowa : (n - 1);

  f32x4 acc[NT];
#pragma unroll
  for (int t = 0; t < NT; ++t) acc[t] = (f32x4)0.f;

#pragma unroll
  for (int ks = 0; ks < 4; ++ks) {
    const int k0 = 32 * ks;
    uint4 av = *(const uint4*)(A + (size_t)ra * FH + k0 + 8 * h);
    if (BN_A) {
      const float4* sc4 = (const float4*)(scA + k0 + 8 * h);
      const float4* sh4 = (const float4*)(shA + k0 + 8 * h);
      float4 sa = sc4[0], sb = sc4[1], ha = sh4[0], hb = sh4[1];
      av.x = pack2(fmaxf(fmaf(bf_lo(av.x), sa.x, ha.x), 0.f),
                   fmaxf(fmaf(bf_hi(av.x), sa.y, ha.y), 0.f));
      av.y = pack2(fmaxf(fmaf(bf_lo(av.y), sa.z, ha.z), 0.f),
                   fmaxf(fmaf(bf_hi(av.y), sa.w, ha.w), 0.f));
      av.z = pack2(fmaxf(fmaf(bf_lo(av.z), sb.x, hb.x), 0.f),
                   fmaxf(fmaf(bf_hi(av.z), sb.y, hb.y), 0.f));
      av.w = pack2(fmaxf(fmaf(bf_lo(av.w), sb.z, hb.z), 0.f),
                   fmaxf(fmaf(bf_hi(av.w), sb.w, hb.w), 0.f));
    }
    bf16x8 afrag = __builtin_bit_cast(bf16x8, av);
    const int kq = ks * 4 + h;
#pragma unroll
    for (int ct = 0; ct < NT; ++ct) {
      int c = ct * 16 + cc;
      uint4 bv = *(const uint4*)(Wt + ((size_t)kq * FOUT + c) * 8);
      bf16x8 bfrag = __builtin_bit_cast(bf16x8, bv);
      acc[ct] = __builtin_amdgcn_mfma_f32_16x16x32_bf16(afrag, bfrag, acc[ct], 0, 0, 0);
    }
  }

  const int rbase = blockIdx.x * 64 + wv * 16 + 4 * h;
#pragma unroll
  for (int ct = 0; ct < NT; ++ct) {
    int c = ct * 16 + cc;
    float bvv = bias ? bias[c] : 0.f;
#pragma unroll
    for (int r = 0; r < 4; ++r) {
      int gr = rbase + r;
      if (gr < n) out[(size_t)gr * FOUT + c] = (ushort_t)f2bf(acc[ct][r] + bvv);
    }
  }
}

// ---------------- fused: gemm0 || padded histogram (fire-and-forget atomics only) --------

__global__ __launch_bounds__(256) void fused_gemm_hist_kernel(
    const float* __restrict__ A, const float* __restrict__ W, void* __restrict__ out, int n,
    int GB, const int* __restrict__ row, const int* __restrict__ col,
    int* __restrict__ degr_p, int* __restrict__ degc_p, int E) {
  int bid = blockIdx.x;
  int r5 = bid % 5;
  int g = bid / 5;
  if (r5 == 0 && g < GB) {
    gemm2_body<F0, FH, 8, 16, false, true>(g, A, W, nullptr, out, n);
    return;
  }
  int h = (r5 == 0) ? (bid - GB) : (bid - (g + 1));
  int e = h * 256 + threadIdx.x;
  if (e >= E) return;
  atomicAdd(&degr_p[(size_t)row[e] * PD], 1);   // no return value used -> fire-and-forget
  atomicAdd(&degc_p[(size_t)col[e] * PD], 1);
}

// ---------------- scan: dinv + block scan of degc + cursor copy + fused partials ----------

__global__ __launch_bounds__(256) void scan_fused_kernel(const int* __restrict__ degr_p,
                                                         const int* __restrict__ degc_p,
                                                         float* __restrict__ dinv,
                                                         int* __restrict__ startp,
                                                         int* __restrict__ cursor,
                                                         int* __restrict__ bsums, int n,
                                                         int* __restrict__ ctr) {
  __shared__ int s[256];
  const int tid = threadIdx.x;
  int i = blockIdx.x * 256 + tid;
  int dc = 0;
  if (i < n) {
    int dr = degr_p[(size_t)i * PD];
    dc = degc_p[(size_t)i * PD];
    dinv[i] = (dr > 0) ? rsqrtf((float)dr) : 0.0f;
  }
  s[tid] = dc;
  __syncthreads();
  for (int off = 1; off < 256; off <<= 1) {
    int t = 0;
    if (tid >= off) t = s[tid - off];
    __syncthreads();
    if (tid >= off) s[tid] += t;
    __syncthreads();
  }
  if (i < n) {
    int sp = s[tid] - dc;
    startp[i] = sp;
    cursor[i] = sp;  // scatter's atomic rank base (block-partial offset)
  }
  if (tid == 255) bsums[blockIdx.x] = s[255];
  __threadfence();
  __syncthreads();
  __shared__ int lastFlag;
  if (tid == 0) lastFlag = (atomicAdd(ctr, 1) == (int)gridDim.x - 1) ? 1 : 0;
  __syncthreads();
  if (!lastFlag) return;
  int nb = (int)gridDim.x;
  int v = (tid < nb) ? atomicAdd(&bsums[tid], 0) : 0;  // coherent re-read
  s[tid] = v;
  __syncthreads();
  for (int off = 1; off < 256; off <<= 1) {
    int t = 0;
    if (tid >= off) t = s[tid - off];
    __syncthreads();
    if (tid >= off) s[tid] += t;
    __syncthreads();
  }
  if (tid < nb) bsums[tid] = s[tid] - v;  // exclusive
}

// ---------------- scatter with cursor atomics: rank assigned here ----------------

__global__ __launch_bounds__(256) void csr_scatter2_kernel(const int* __restrict__ row,
                                                           const int* __restrict__ col,
                                                           const float* __restrict__ ew,
                                                           const float* __restrict__ dinv,
                                                           int* __restrict__ cursor,
                                                           const int* __restrict__ bsums,
                                                           int2* __restrict__ ep, int E) {
  int e = blockIdx.x * blockDim.x + threadIdx.x;
  if (e >= E) return;
  int r = row[e], c = col[e];
  int pos = atomicAdd(&cursor[c], 1) + bsums[c >> 8];
  float coef = dinv[r] * ew[e] * dinv[c];
  ep[pos] = make_int2(r, __float_as_int(coef));
}

// ---------------- conv gather (bf16 in), thread = (dst, q): 2 uint4 chunks ----------------

template <int F, bool DO_BN, bool OUT_F32>
__global__ __launch_bounds__(256) void conv_kernel(const ushort_t* __restrict__ x,
                                                   const int* __restrict__ startp,
                                                   const int* __restrict__ bsums,
                                                   const int* __restrict__ degc_p,
                                                   const int2* __restrict__ ep,
                                                   const float* __restrict__ bias,
                                                   const float* __restrict__ scale,
                                                   const float* __restrict__ shift,
                                                   void* __restrict__ out, int n) {
  constexpr int G2 = F / 8;
  constexpr int TPD = G2 / 2;
  long long tid = (long long)blockIdx.x * 256 + threadIdx.x;
  if (tid >= (long long)n * TPD) return;
  int dst = (int)(tid / TPD);
  int q = (int)(tid % TPD);
  int s0 = startp[dst] + bsums[dst >> 8];
  int d = degc_p[(size_t)dst * PD];
  const uint4* x4 = (const uint4*)x;

  float sc[16], sh[16];
  if (DO_BN) {
#pragma unroll
    for (int ch = 0; ch < 2; ++ch) {
      int g = q + ch * TPD;
#pragma unroll
      for (int j = 0; j < 8; ++j) {
        sc[ch * 8 + j] = scale[g * 8 + j];
        sh[ch * 8 + j] = shift[g * 8 + j];
      }
    }
  }

  float acc[16];
#pragma unroll
  for (int j = 0; j < 16; ++j) acc[j] = 0.f;

  for (int k = 0; k < d; ++k) {
    int2 e = ep[s0 + k];
    float c = __int_as_float(e.y);
    const uint4* xp = x4 + (size_t)e.x * G2 + q;
    uint4 v0 = xp[0];
    uint4 v1 = xp[TPD];
    uint_t vv[8] = {v0.x, v0.y, v0.z, v0.w, v1.x, v1.y, v1.z, v1.w};
#pragma unroll
    for (int hh = 0; hh < 8; ++hh) {
      float f0 = bf_lo(vv[hh]);
      float f1 = bf_hi(vv[hh]);
      if (DO_BN) {
        f0 = fmaxf(fmaf(f0, sc[2 * hh], sh[2 * hh]), 0.f);
        f1 = fmaxf(fmaf(f1, sc[2 * hh + 1], sh[2 * hh + 1]), 0.f);
      }
      acc[2 * hh] = fmaf(c, f0, acc[2 * hh]);
      acc[2 * hh + 1] = fmaf(c, f1, acc[2 * hh + 1]);
    }
  }

  if (bias) {
#pragma unroll
    for (int ch = 0; ch < 2; ++ch) {
      int g = q + ch * TPD;
#pragma unroll
      for (int j = 0; j < 8; ++j) acc[ch * 8 + j] += bias[g * 8 + j];
    }
  }

  if (OUT_F32) {
    float4* o4 = (float4*)out;
    size_t base = (size_t)dst * (F / 4);
    o4[base + 2 * q] = make_float4(acc[0], acc[1], acc[2], acc[3]);
    o4[base + 2 * q + 1] = make_float4(acc[4], acc[5], acc[6], acc[7]);
    o4[base + 2 * (q + TPD)] = make_float4(acc[8], acc[9], acc[10], acc[11]);
    o4[base + 2 * (q + TPD) + 1] = make_float4(acc[12], acc[13], acc[14], acc[15]);
  } else {
    uint4* o4 = (uint4*)out;
    size_t base = (size_t)dst * G2;
    o4[base + q] = make_uint4(pack2(acc[0], acc[1]), pack2(acc[2], acc[3]),
                              pack2(acc[4], acc[5]), pack2(acc[6], acc[7]));
    o4[base + q + TPD] = make_uint4(pack2(acc[8], acc[9]), pack2(acc[10], acc[11]),
                                    pack2(acc[12], acc[13]), pack2(acc[14], acc[15]));
  }
}

// ---------------- fast BN stats: coalesced uint4 reads + LDS reduce + last-block finalize --

__global__ __launch_bounds__(256) void bn_stats_fast_kernel(const ushort_t* __restrict__ z,
                                                            float* __restrict__ sum,
                                                            float* __restrict__ sumsq,
                                                            const float* __restrict__ g,
                                                            const float* __restrict__ be,
                                                            float* __restrict__ scale,
                                                            float* __restrict__ shift,
                                                            int n, int* __restrict__ ctr) {
  const int tid = threadIdx.x;
  const int q = tid & 15;
  const int rg = tid >> 4;
  const uint4* z4 = (const uint4*)z;

  float s[8], s2[8];
#pragma unroll
  for (int j = 0; j < 8; ++j) { s[j] = 0.f; s2[j] = 0.f; }

  for (int r = blockIdx.x * 16 + rg; r < n; r += (int)gridDim.x * 16) {
    uint4 v = z4[(size_t)r * (FH / 8) + q];
    uint_t vv[4] = {v.x, v.y, v.z, v.w};
#pragma unroll
    for (int h = 0; h < 4; ++h) {
      float f0 = bf_lo(vv[h]);
      float f1 = bf_hi(vv[h]);
      s[2 * h] += f0;      s2[2 * h] += f0 * f0;
      s[2 * h + 1] += f1;  s2[2 * h + 1] += f1 * f1;
    }
  }

  __shared__ float red[256][8];
#pragma unroll
  for (int j = 0; j < 8; ++j) red[tid][j] = s[j];
  __syncthreads();
  for (int off = 128; off >= 16; off >>= 1) {
    if (tid < off) {
#pragma unroll
      for (int j = 0; j < 8; ++j) red[tid][j] += red[tid + off][j];
    }
    __syncthreads();
  }
  if (tid < 16) {
#pragma unroll
    for (int j = 0; j < 8; ++j) unsafeAtomicAdd(&sum[8 * tid + j], red[tid][j]);
  }
  __syncthreads();
#pragma unroll
  for (int j = 0; j < 8; ++j) red[tid][j] = s2[j];
  __syncthreads();
  for (int off = 128; off >= 16; off >>= 1) {
    if (tid < off) {
#pragma unroll
      for (int j = 0; j < 8; ++j) red[tid][j] += red[tid + off][j];
    }
    __syncthreads();
  }
  if (tid < 16) {
#pragma unroll
    for (int j = 0; j < 8; ++j) unsafeAtomicAdd(&sumsq[8 * tid + j], red[tid][j]);
  }
  __threadfence();
  __syncthreads();
  __shared__ int lastFlag;
  if (tid == 0) lastFlag = (atomicAdd(ctr, 1) == (int)gridDim.x - 1) ? 1 : 0;
  __syncthreads();
  if (lastFlag && tid < FH) {
    float S = atomicAdd(&sum[tid], 0.0f);
    float S2 = atomicAdd(&sumsq[tid], 0.0f);
    float invN = 1.0f / (float)n;
    float mean = S * invN;
    float var = fmaxf(S2 * invN - mean * mean, 0.0f);
    float sc = g[tid] / sqrtf(var + BN_EPS);
    scale[tid] = sc;
    shift[tid] = be[tid] - mean * sc;
  }
}

// ---------------- launch ----------------

extern "C" void kernel_launch(void* const* d_in, const int* in_sizes, int n_in,
                              void* d_out, int out_size, void* d_ws, size_t ws_size,
                              hipStream_t stream) {
  const float* x   = (const float*)d_in[0];
  const int*   ei  = (const int*)d_in[1];
  const float* ew  = (const float*)d_in[2];
  const float* W0  = (const float*)d_in[3];
  const float* b0  = (const float*)d_in[4];
  const float* g0  = (const float*)d_in[5];
  const float* be0 = (const float*)d_in[6];
  const float* W1  = (const float*)d_in[7];
  const float* b1  = (const float*)d_in[8];
  const float* g1  = (const float*)d_in[9];
  const float* be1 = (const float*)d_in[10];
  const float* W2  = (const float*)d_in[11];
  const float* b2  = (const float*)d_in[12];

  const int n = in_sizes[0] / F0;
  const int E = in_sizes[2];
  const int* row = ei;
  const int* col = ei + E;

  // workspace layout
  ushort_t* bufA  = (ushort_t*)d_ws;                    // n*FH bf16 (t0 -> conv1-out -> t2)
  ushort_t* bufB  = bufA + (size_t)n * FH;              // n*FH bf16 (z0 -> z1)
  int2*   ep      = (int2*)(bufB + (size_t)n * FH);     // E int2
  // ---- contiguous zero region: [degc_p | degr_p | sums | ctrs] ----
  int*    degc_p  = (int*)(ep + E);                     // n*PD
  int*    degr_p  = degc_p + (size_t)n * PD;            // n*PD
  float*  sum0    = (float*)(degr_p + (size_t)n * PD);  // 128
  float*  sumsq0  = sum0 + FH;                          // 128
  float*  sum1    = sumsq0 + FH;                        // 128
  float*  sumsq1  = sum1 + FH;                          // 128
  int*    ctr     = (int*)(sumsq1 + FH);                // 3 (scan, stats0, stats1)
  const size_t zero_bytes = (2 * (size_t)n * PD + 4 * FH + 3) * 4;
  // ---- rest ----
  int*    startp  = ctr + 3;                            // n
  int*    cursor  = startp + n;                         // n (scatter rank cursor)
  float*  dinv    = (float*)(cursor + n);               // n
  int*    bsums   = (int*)(dinv + n);                   // 256
  float*  scale0  = (float*)(bsums + 256);              // 128
  float*  shift0  = scale0 + FH;
  float*  scale1  = shift0 + FH;
  float*  shift1  = scale1 + FH;

  const int nb = ceil_div(n, 256);          // <= 256 required by fused scan
  const int GB = ceil_div(n, 64);           // gemm0 blocks (BR=64)
  const int HB = ceil_div(E, 256);          // edge blocks
  const int MB = ceil_div(n, 64);           // mfma gemm blocks
  const int CB_H = ceil_div((long long)n * (FH / 16), 256);  // conv F=128
  const int CB_O = ceil_div((long long)n * (FO / 16), 256);  // conv F=64

  // 1. zero counters/stats
  (void)hipMemsetAsync(degc_p, 0, zero_bytes, stream);
  // 2. fused {gemm0: t0 = x@W0 -> bufA bf16} || {padded histogram, no returning atomics}
  fused_gemm_hist_kernel<<<GB + HB, 256, 0, stream>>>(x, W0, bufA, n, GB, row, col,
                                                      degr_p, degc_p, E);
  // 3. scan (block scans + cursor copy + fused partials via last-block-done)
  scan_fused_kernel<<<nb, 256, 0, stream>>>(degr_p, degc_p, dinv, startp, cursor, bsums, n,
                                            ctr + 0);
  // 4. scatter (rank via cursor atomics)
  csr_scatter2_kernel<<<HB, 256, 0, stream>>>(row, col, ew, dinv, cursor, bsums, ep, E);
  // 5. z0 = conv(t0) + b0 -> bufB
  conv_kernel<FH, false, false><<<CB_H, 256, 0, stream>>>(
      bufA, startp, bsums, degc_p, ep, b0, nullptr, nullptr, bufB, n);
  // 6. stats0 + finalize -> scale0/shift0
  bn_stats_fast_kernel<<<128, 256, 0, stream>>>(bufB, sum0, sumsq0, g0, be0, scale0, shift0,
                                                n, ctr + 1);
  // 7. conv(relu(bn0(z0))) -> bufA
  conv_kernel<FH, true, false><<<CB_H, 256, 0, stream>>>(
      bufB, startp, bsums, degc_p, ep, nullptr, scale0, shift0, bufA, n);
  // 8. z1 = bufA @ W1 + b1 -> bufB (MFMA)
  gemm_mfma_kernel<FH, false><<<MB, 256, 0, stream>>>(bufA, W1, b1, nullptr, nullptr, bufB, n);
  // 9. stats1 + finalize -> scale1/shift1
  bn_stats_fast_kernel<<<128, 256, 0, stream>>>(bufB, sum1, sumsq1, g1, be1, scale1, shift1,
                                                n, ctr + 2);
  // 10. t2 = relu(bn1(z1)) @ W2 -> bufA (n x 64 bf16, MFMA, BN fused on A-loads)
  gemm_mfma_kernel<FO, true><<<MB, 256, 0, stream>>>(bufB, W2, nullptr, scale1, shift1, bufA, n);
  // 11. out = conv(t2) + b2 -> d_out (fp32)
  conv_kernel<FO, false, true><<<CB_O, 256, 0, stream>>>(
      bufA, startp, bsums, degc_p, ep, b2, nullptr, nullptr, (float*)d_out, n);
}

// Round 18
// 342.171 us; speedup vs baseline: 6.5364x; 1.0627x over previous
//
#include <hip/hip_runtime.h>
#include <cstdint>

#define F0 100
#define FH 128
#define FO 64
#define PD 4  // counter padding (ints)
#define BN_EPS 1e-5f

typedef unsigned short ushort_t;
typedef unsigned int uint_t;
typedef __attribute__((ext_vector_type(8))) __bf16 bf16x8;
typedef __attribute__((ext_vector_type(4))) float f32x4;

static inline int ceil_div(long long a, long long b) { return (int)((a + b - 1) / b); }

// ---- bf16 helpers (fp32 math everywhere; bf16 is storage only) ----
__device__ __forceinline__ float bf_lo(uint_t w) { return __uint_as_float(w << 16); }
__device__ __forceinline__ float bf_hi(uint_t w) { return __uint_as_float(w & 0xffff0000u); }
__device__ __forceinline__ uint_t f2bf(float f) {  // RNE
  uint_t u = __float_as_uint(f);
  return (u + 0x7fffu + ((u >> 16) & 1u)) >> 16;
}
__device__ __forceinline__ uint_t pack2(float a, float b) {
  return f2bf(a) | (f2bf(b) << 16);
}

// ---------------- GEMM body (vector fp32; used for gemm0 inside hist) ----------------

template <int K, int F, int TM, int BK, bool A_BF16, bool OUT_BF16>
__device__ __forceinline__ void gemm2_body(int bid, const void* __restrict__ A_,
                                           const float* __restrict__ W,
                                           const float* __restrict__ bias,
                                           void* __restrict__ out_, int n) {
  constexpr int NCG = F / 4;
  constexpr int NRG = 256 / NCG;
  constexpr int BR = NRG * TM;
  constexpr int F4 = F / 4;

  __shared__ float sW[BK][F];
  __shared__ float sA[BR][BK];

  const int tid = threadIdx.x;
  const int cg = tid % NCG;
  const int rg = tid / NCG;
  const int row0 = bid * BR;

  float4 acc[TM];
#pragma unroll
  for (int t = 0; t < TM; ++t) acc[t] = make_float4(0.f, 0.f, 0.f, 0.f);

  const float4* W4 = (const float4*)W;
  const float4 z4 = make_float4(0.f, 0.f, 0.f, 0.f);

  for (int k0 = 0; k0 < K; k0 += BK) {
    for (int i = tid; i < BK * F4; i += 256) {
      int kk = i / F4, f4 = i % F4;
      int gk = k0 + kk;
      ((float4*)&sW[kk][0])[f4] = (gk < K) ? W4[(size_t)gk * F4 + f4] : z4;
    }
    for (int i = tid; i < BR * (BK / 4); i += 256) {
      int r = i / (BK / 4), k4 = i % (BK / 4);
      int gr = row0 + r;
      int gk = k0 + k4 * 4;
      float4 av = z4;
      if (gr < n && gk + 3 < K) {
        if (A_BF16) {
          uint2 u = ((const uint2*)A_)[(size_t)gr * (K / 4) + (gk >> 2)];
          av.x = bf_lo(u.x); av.y = bf_hi(u.x);
          av.z = bf_lo(u.y); av.w = bf_hi(u.y);
        } else {
          av = ((const float4*)A_)[(size_t)gr * (K / 4) + (gk >> 2)];
        }
      }
      ((float4*)&sA[r][0])[k4] = av;
    }
    __syncthreads();
#pragma unroll 4
    for (int kk = 0; kk < BK; ++kk) {
      float4 w = ((const float4*)&sW[kk][0])[cg];
#pragma unroll
      for (int t = 0; t < TM; ++t) {
        float a = sA[rg * TM + t][kk];
        acc[t].x = fmaf(a, w.x, acc[t].x);
        acc[t].y = fmaf(a, w.y, acc[t].y);
        acc[t].z = fmaf(a, w.z, acc[t].z);
        acc[t].w = fmaf(a, w.w, acc[t].w);
      }
    }
    __syncthreads();
  }

  float4 bb = bias ? ((const float4*)bias)[cg] : z4;
#pragma unroll
  for (int t = 0; t < TM; ++t) {
    int gr = row0 + rg * TM + t;
    if (gr < n) {
      float4 v = acc[t];
      v.x += bb.x; v.y += bb.y; v.z += bb.z; v.w += bb.w;
      if (OUT_BF16) {
        ((uint2*)out_)[(size_t)gr * F4 + cg] = make_uint2(pack2(v.x, v.y), pack2(v.z, v.w));
      } else {
        ((float4*)out_)[(size_t)gr * F4 + cg] = v;
      }
    }
  }
}

// ---------------- MFMA GEMM: out[n x FOUT] bf16 = A[n x 128] bf16 @ W[128 x FOUT] fp32 ----

template <int FOUT, bool BN_A>
__global__ __launch_bounds__(256) void gemm_mfma_kernel(const ushort_t* __restrict__ A,
                                                        const float* __restrict__ W,
                                                        const float* __restrict__ bias,
                                                        const float* __restrict__ scA,
                                                        const float* __restrict__ shA,
                                                        ushort_t* __restrict__ out, int n) {
  constexpr int F4 = FOUT / 4;
  constexpr int NT = FOUT / 16;
  __shared__ ushort_t Wt[16 * FOUT * 8];  // [kq=K/8][c][8 k-elems]

  const int tid = threadIdx.x;
  const float4* W4 = (const float4*)W;
  uint_t* w32 = (uint_t*)Wt;
  for (int idx = tid; idx < 64 * F4; idx += 256) {
    int kp = idx / F4, cq = idx % F4;
    float4 wa = W4[(size_t)(2 * kp) * F4 + cq];
    float4 wb = W4[(size_t)(2 * kp + 1) * F4 + cq];
    int kq = kp >> 2, e2 = kp & 3;
    int base = (kq * FOUT + cq * 4) * 4 + e2;
    w32[base]      = pack2(wa.x, wb.x);
    w32[base + 4]  = pack2(wa.y, wb.y);
    w32[base + 8]  = pack2(wa.z, wb.z);
    w32[base + 12] = pack2(wa.w, wb.w);
  }
  __syncthreads();

  const int l = tid & 63;
  const int wv = tid >> 6;
  const int cc = l & 15;
  const int h = l >> 4;
  const int rowa = blockIdx.x * 64 + wv * 16 + cc;
  const int ra = (rowa < n) ? rowa : (n - 1);

  f32x4 acc[NT];
#pragma unroll
  for (int t = 0; t < NT; ++t) acc[t] = (f32x4)0.f;

#pragma unroll
  for (int ks = 0; ks < 4; ++ks) {
    const int k0 = 32 * ks;
    uint4 av = *(const uint4*)(A + (size_t)ra * FH + k0 + 8 * h);
    if (BN_A) {
      const float4* sc4 = (const float4*)(scA + k0 + 8 * h);
      const float4* sh4 = (const float4*)(shA + k0 + 8 * h);
      float4 sa = sc4[0], sb = sc4[1], ha = sh4[0], hb = sh4[1];
      av.x = pack2(fmaxf(fmaf(bf_lo(av.x), sa.x, ha.x), 0.f),
                   fmaxf(fmaf(bf_hi(av.x), sa.y, ha.y), 0.f));
      av.y = pack2(fmaxf(fmaf(bf_lo(av.y), sa.z, ha.z), 0.f),
                   fmaxf(fmaf(bf_hi(av.y), sa.w, ha.w), 0.f));
      av.z = pack2(fmaxf(fmaf(bf_lo(av.z), sb.x, hb.x), 0.f),
                   fmaxf(fmaf(bf_hi(av.z), sb.y, hb.y), 0.f));
      av.w = pack2(fmaxf(fmaf(bf_lo(av.w), sb.z, hb.z), 0.f),
                   fmaxf(fmaf(bf_hi(av.w), sb.w, hb.w), 0.f));
    }
    bf16x8 afrag = __builtin_bit_cast(bf16x8, av);
    const int kq = ks * 4 + h;
#pragma unroll
    for (int ct = 0; ct < NT; ++ct) {
      int c = ct * 16 + cc;
      uint4 bv = *(const uint4*)(Wt + ((size_t)kq * FOUT + c) * 8);
      bf16x8 bfrag = __builtin_bit_cast(bf16x8, bv);
      acc[ct] = __builtin_amdgcn_mfma_f32_16x16x32_bf16(afrag, bfrag, acc[ct], 0, 0, 0);
    }
  }

  const int rbase = blockIdx.x * 64 + wv * 16 + 4 * h;
#pragma unroll
  for (int ct = 0; ct < NT; ++ct) {
    int c = ct * 16 + cc;
    float bvv = bias ? bias[c] : 0.f;
#pragma unroll
    for (int r = 0; r < 4; ++r) {
      int gr = rbase + r;
      if (gr < n) out[(size_t)gr * FOUT + c] = (ushort_t)f2bf(acc[ct][r] + bvv);
    }
  }
}

// ---------------- fused: gemm0 (x@W0 -> bufA bf16, BK=16) || padded histogram ----------------

__global__ __launch_bounds__(256) void fused_gemm_hist_kernel(
    const float* __restrict__ A, const float* __restrict__ W, void* __restrict__ out, int n,
    int GB, const int* __restrict__ row, const int* __restrict__ col,
    int* __restrict__ degr_p, int* __restrict__ degc_p, int* __restrict__ posw, int E) {
  int bid = blockIdx.x;
  int r5 = bid % 5;
  int g = bid / 5;
  if (r5 == 0 && g < GB) {
    gemm2_body<F0, FH, 8, 16, false, true>(g, A, W, nullptr, out, n);
    return;
  }
  int h = (r5 == 0) ? (bid - GB) : (bid - (g + 1));
  int e = h * 256 + threadIdx.x;
  if (e >= E) return;
  atomicAdd(&degr_p[(size_t)row[e] * PD], 1);
  posw[e] = atomicAdd(&degc_p[(size_t)col[e] * PD], 1);
}

// ---------------- scan: dinv + block scan of degc + fused partials (last-block-done) ------

__global__ __launch_bounds__(256) void scan_fused_kernel(const int* __restrict__ degr_p,
                                                         const int* __restrict__ degc_p,
                                                         float* __restrict__ dinv,
                                                         int* __restrict__ startp,
                                                         int* __restrict__ bsums, int n,
                                                         int* __restrict__ ctr) {
  __shared__ int s[256];
  const int tid = threadIdx.x;
  int i = blockIdx.x * 256 + tid;
  int dc = 0;
  if (i < n) {
    int dr = degr_p[(size_t)i * PD];
    dc = degc_p[(size_t)i * PD];
    dinv[i] = (dr > 0) ? rsqrtf((float)dr) : 0.0f;
  }
  s[tid] = dc;
  __syncthreads();
  for (int off = 1; off < 256; off <<= 1) {
    int t = 0;
    if (tid >= off) t = s[tid - off];
    __syncthreads();
    if (tid >= off) s[tid] += t;
    __syncthreads();
  }
  if (i < n) startp[i] = s[tid] - dc;
  if (tid == 255) bsums[blockIdx.x] = s[255];
  __threadfence();
  __syncthreads();
  __shared__ int lastFlag;
  if (tid == 0) lastFlag = (atomicAdd(ctr, 1) == (int)gridDim.x - 1) ? 1 : 0;
  __syncthreads();
  if (!lastFlag) return;
  int nb = (int)gridDim.x;
  int v = (tid < nb) ? atomicAdd(&bsums[tid], 0) : 0;  // coherent re-read
  s[tid] = v;
  __syncthreads();
  for (int off = 1; off < 256; off <<= 1) {
    int t = 0;
    if (tid >= off) t = s[tid - off];
    __syncthreads();
    if (tid >= off) s[tid] += t;
    __syncthreads();
  }
  if (tid < nb) bsums[tid] = s[tid] - v;  // exclusive
}

// ---------------- atomic-free scatter of packed (src, coef) into dst-bucket order --------

__global__ __launch_bounds__(256) void csr_scatter2_kernel(const int* __restrict__ row,
                                                           const int* __restrict__ col,
                                                           const float* __restrict__ ew,
                                                           const float* __restrict__ dinv,
                                                           const int* __restrict__ startp,
                                                           const int* __restrict__ bsums,
                                                           const int* __restrict__ posw,
                                                           int2* __restrict__ ep, int E) {
  int e = blockIdx.x * blockDim.x + threadIdx.x;
  if (e >= E) return;
  int r = row[e], c = col[e];
  int pos = startp[c] + bsums[c >> 8] + posw[e];
  float coef = dinv[r] * ew[e] * dinv[c];
  ep[pos] = make_int2(r, __float_as_int(coef));
}

// ---------------- conv gather (bf16 in), thread = (dst, q): 2 uint4 chunks ----------------

template <int F, bool DO_BN, bool OUT_F32>
__global__ __launch_bounds__(256) void conv_kernel(const ushort_t* __restrict__ x,
                                                   const int* __restrict__ startp,
                                                   const int* __restrict__ bsums,
                                                   const int* __restrict__ degc_p,
                                                   const int2* __restrict__ ep,
                                                   const float* __restrict__ bias,
                                                   const float* __restrict__ scale,
                                                   const float* __restrict__ shift,
                                                   void* __restrict__ out, int n) {
  constexpr int G2 = F / 8;
  constexpr int TPD = G2 / 2;
  long long tid = (long long)blockIdx.x * 256 + threadIdx.x;
  if (tid >= (long long)n * TPD) return;
  int dst = (int)(tid / TPD);
  int q = (int)(tid % TPD);
  int s0 = startp[dst] + bsums[dst >> 8];
  int d = degc_p[(size_t)dst * PD];
  const uint4* x4 = (const uint4*)x;

  float sc[16], sh[16];
  if (DO_BN) {
#pragma unroll
    for (int ch = 0; ch < 2; ++ch) {
      int g = q + ch * TPD;
#pragma unroll
      for (int j = 0; j < 8; ++j) {
        sc[ch * 8 + j] = scale[g * 8 + j];
        sh[ch * 8 + j] = shift[g * 8 + j];
      }
    }
  }

  float acc[16];
#pragma unroll
  for (int j = 0; j < 16; ++j) acc[j] = 0.f;

  for (int k = 0; k < d; ++k) {
    int2 e = ep[s0 + k];
    float c = __int_as_float(e.y);
    const uint4* xp = x4 + (size_t)e.x * G2 + q;
    uint4 v0 = xp[0];
    uint4 v1 = xp[TPD];
    uint_t vv[8] = {v0.x, v0.y, v0.z, v0.w, v1.x, v1.y, v1.z, v1.w};
#pragma unroll
    for (int hh = 0; hh < 8; ++hh) {
      float f0 = bf_lo(vv[hh]);
      float f1 = bf_hi(vv[hh]);
      if (DO_BN) {
        f0 = fmaxf(fmaf(f0, sc[2 * hh], sh[2 * hh]), 0.f);
        f1 = fmaxf(fmaf(f1, sc[2 * hh + 1], sh[2 * hh + 1]), 0.f);
      }
      acc[2 * hh] = fmaf(c, f0, acc[2 * hh]);
      acc[2 * hh + 1] = fmaf(c, f1, acc[2 * hh + 1]);
    }
  }

  if (bias) {
#pragma unroll
    for (int ch = 0; ch < 2; ++ch) {
      int g = q + ch * TPD;
#pragma unroll
      for (int j = 0; j < 8; ++j) acc[ch * 8 + j] += bias[g * 8 + j];
    }
  }

  if (OUT_F32) {
    float4* o4 = (float4*)out;
    size_t base = (size_t)dst * (F / 4);
    o4[base + 2 * q] = make_float4(acc[0], acc[1], acc[2], acc[3]);
    o4[base + 2 * q + 1] = make_float4(acc[4], acc[5], acc[6], acc[7]);
    o4[base + 2 * (q + TPD)] = make_float4(acc[8], acc[9], acc[10], acc[11]);
    o4[base + 2 * (q + TPD) + 1] = make_float4(acc[12], acc[13], acc[14], acc[15]);
  } else {
    uint4* o4 = (uint4*)out;
    size_t base = (size_t)dst * G2;
    o4[base + q] = make_uint4(pack2(acc[0], acc[1]), pack2(acc[2], acc[3]),
                              pack2(acc[4], acc[5]), pack2(acc[6], acc[7]));
    o4[base + q + TPD] = make_uint4(pack2(acc[8], acc[9]), pack2(acc[10], acc[11]),
                                    pack2(acc[12], acc[13]), pack2(acc[14], acc[15]));
  }
}

// ---------------- fast BN stats: coalesced uint4 reads + LDS reduce + last-block finalize --

__global__ __launch_bounds__(256) void bn_stats_fast_kernel(const ushort_t* __restrict__ z,
                                                            float* __restrict__ sum,
                                                            float* __restrict__ sumsq,
                                                            const float* __restrict__ g,
                                                            const float* __restrict__ be,
                                                            float* __restrict__ scale,
                                                            float* __restrict__ shift,
                                                            int n, int* __restrict__ ctr) {
  const int tid = threadIdx.x;
  const int q = tid & 15;
  const int rg = tid >> 4;
  const uint4* z4 = (const uint4*)z;

  float s[8], s2[8];
#pragma unroll
  for (int j = 0; j < 8; ++j) { s[j] = 0.f; s2[j] = 0.f; }

  for (int r = blockIdx.x * 16 + rg; r < n; r += (int)gridDim.x * 16) {
    uint4 v = z4[(size_t)r * (FH / 8) + q];
    uint_t vv[4] = {v.x, v.y, v.z, v.w};
#pragma unroll
    for (int h = 0; h < 4; ++h) {
      float f0 = bf_lo(vv[h]);
      float f1 = bf_hi(vv[h]);
      s[2 * h] += f0;      s2[2 * h] += f0 * f0;
      s[2 * h + 1] += f1;  s2[2 * h + 1] += f1 * f1;
    }
  }

  __shared__ float red[256][8];
#pragma unroll
  for (int j = 0; j < 8; ++j) red[tid][j] = s[j];
  __syncthreads();
  for (int off = 128; off >= 16; off >>= 1) {
    if (tid < off) {
#pragma unroll
      for (int j = 0; j < 8; ++j) red[tid][j] += red[tid + off][j];
    }
    __syncthreads();
  }
  if (tid < 16) {
#pragma unroll
    for (int j = 0; j < 8; ++j) unsafeAtomicAdd(&sum[8 * tid + j], red[tid][j]);
  }
  __syncthreads();
#pragma unroll
  for (int j = 0; j < 8; ++j) red[tid][j] = s2[j];
  __syncthreads();
  for (int off = 128; off >= 16; off >>= 1) {
    if (tid < off) {
#pragma unroll
      for (int j = 0; j < 8; ++j) red[tid][j] += red[tid + off][j];
    }
    __syncthreads();
  }
  if (tid < 16) {
#pragma unroll
    for (int j = 0; j < 8; ++j) unsafeAtomicAdd(&sumsq[8 * tid + j], red[tid][j]);
  }
  __threadfence();
  __syncthreads();
  __shared__ int lastFlag;
  if (tid == 0) lastFlag = (atomicAdd(ctr, 1) == (int)gridDim.x - 1) ? 1 : 0;
  __syncthreads();
  if (lastFlag && tid < FH) {
    float S = atomicAdd(&sum[tid], 0.0f);
    float S2 = atomicAdd(&sumsq[tid], 0.0f);
    float invN = 1.0f / (float)n;
    float mean = S * invN;
    float var = fmaxf(S2 * invN - mean * mean, 0.0f);
    float sc = g[tid] / sqrtf(var + BN_EPS);
    scale[tid] = sc;
    shift[tid] = be[tid] - mean * sc;
  }
}

// ---------------- launch ----------------

extern "C" void kernel_launch(void* const* d_in, const int* in_sizes, int n_in,
                              void* d_out, int out_size, void* d_ws, size_t ws_size,
                              hipStream_t stream) {
  const float* x   = (const float*)d_in[0];
  const int*   ei  = (const int*)d_in[1];
  const float* ew  = (const float*)d_in[2];
  const float* W0  = (const float*)d_in[3];
  const float* b0  = (const float*)d_in[4];
  const float* g0  = (const float*)d_in[5];
  const float* be0 = (const float*)d_in[6];
  const float* W1  = (const float*)d_in[7];
  const float* b1  = (const float*)d_in[8];
  const float* g1  = (const float*)d_in[9];
  const float* be1 = (const float*)d_in[10];
  const float* W2  = (const float*)d_in[11];
  const float* b2  = (const float*)d_in[12];

  const int n = in_sizes[0] / F0;
  const int E = in_sizes[2];
  const int* row = ei;
  const int* col = ei + E;

  // workspace layout
  ushort_t* bufA  = (ushort_t*)d_ws;                    // n*FH bf16 (t0 -> conv1-out -> t2)
  ushort_t* bufB  = bufA + (size_t)n * FH;              // n*FH bf16 (z0 -> z1)
  int2*   ep      = (int2*)(bufB + (size_t)n * FH);     // E int2
  // ---- contiguous zero region: [degc_p | degr_p | sums | ctrs] ----
  int*    degc_p  = (int*)(ep + E);                     // n*PD
  int*    degr_p  = degc_p + (size_t)n * PD;            // n*PD
  float*  sum0    = (float*)(degr_p + (size_t)n * PD);  // 128
  float*  sumsq0  = sum0 + FH;                          // 128
  float*  sum1    = sumsq0 + FH;                        // 128
  float*  sumsq1  = sum1 + FH;                          // 128
  int*    ctr     = (int*)(sumsq1 + FH);                // 3 (scan, stats0, stats1)
  const size_t zero_bytes = (2 * (size_t)n * PD + 4 * FH + 3) * 4;
  // ---- rest ----
  int*    startp  = ctr + 3;                            // n
  float*  dinv    = (float*)(startp + n);               // n
  int*    bsums   = (int*)(dinv + n);                   // 256
  float*  scale0  = (float*)(bsums + 256);              // 128
  float*  shift0  = scale0 + FH;
  float*  scale1  = shift0 + FH;
  float*  shift1  = scale1 + FH;
  // transient: posw aliases bufB (consumed by scatter before bufB first written)
  int*    posw    = (int*)bufB;                         // E ints

  const int nb = ceil_div(n, 256);          // <= 256 required by fused scan
  const int GB = ceil_div(n, 64);           // gemm0 blocks (BR=64)
  const int HB = ceil_div(E, 256);          // edge blocks
  const int MB = ceil_div(n, 64);           // mfma gemm blocks
  const int CB_H = ceil_div((long long)n * (FH / 16), 256);  // conv F=128
  const int CB_O = ceil_div((long long)n * (FO / 16), 256);  // conv F=64

  // 1. zero counters/stats
  (void)hipMemsetAsync(degc_p, 0, zero_bytes, stream);
  // 2. fused {gemm0: t0 = x@W0 -> bufA bf16} || {padded histogram + posw}
  fused_gemm_hist_kernel<<<GB + HB, 256, 0, stream>>>(x, W0, bufA, n, GB, row, col,
                                                      degr_p, degc_p, posw, E);
  // 3. scan (block scans + fused partials via last-block-done)
  scan_fused_kernel<<<nb, 256, 0, stream>>>(degr_p, degc_p, dinv, startp, bsums, n, ctr + 0);
  // 4. scatter
  csr_scatter2_kernel<<<HB, 256, 0, stream>>>(row, col, ew, dinv, startp, bsums, posw, ep, E);
  // 5. z0 = conv(t0) + b0 -> bufB
  conv_kernel<FH, false, false><<<CB_H, 256, 0, stream>>>(
      bufA, startp, bsums, degc_p, ep, b0, nullptr, nullptr, bufB, n);
  // 6. stats0 + finalize -> scale0/shift0
  bn_stats_fast_kernel<<<128, 256, 0, stream>>>(bufB, sum0, sumsq0, g0, be0, scale0, shift0,
                                                n, ctr + 1);
  // 7. conv(relu(bn0(z0))) -> bufA
  conv_kernel<FH, true, false><<<CB_H, 256, 0, stream>>>(
      bufB, startp, bsums, degc_p, ep, nullptr, scale0, shift0, bufA, n);
  // 8. z1 = bufA @ W1 + b1 -> bufB (MFMA)
  gemm_mfma_kernel<FH, false><<<MB, 256, 0, stream>>>(bufA, W1, b1, nullptr, nullptr, bufB, n);
  // 9. stats1 + finalize -> scale1/shift1
  bn_stats_fast_kernel<<<128, 256, 0, stream>>>(bufB, sum1, sumsq1, g1, be1, scale1, shift1,
                                                n, ctr + 2);
  // 10. t2 = relu(bn1(z1)) @ W2 -> bufA (n x 64 bf16, MFMA, BN fused on A-loads)
  gemm_mfma_kernel<FO, true><<<MB, 256, 0, stream>>>(bufB, W2, nullptr, scale1, shift1, bufA, n);
  // 11. out = conv(t2) + b2 -> d_out (fp32)
  conv_kernel<FO, false, true><<<CB_O, 256, 0, stream>>>(
      bufA, startp, bsums, degc_p, ep, b2, nullptr, nullptr, (float*)d_out, n);
}